// Round 7
// baseline (325.587 us; speedup 1.0000x reference)
//
#include <hip/hip_runtime.h>
#include <hip/hip_bf16.h>
#include <hip/hip_fp16.h>
#include <type_traits>

constexpr int BB = 4;
constexpr int CC = 512;
constexpr int HH = 4096;
constexpr int IC = 256;

typedef _Float16 f16x8v __attribute__((ext_vector_type(8)));
typedef __bf16   bf16x8v __attribute__((ext_vector_type(8)));
typedef float    f32x4v __attribute__((ext_vector_type(4)));

__device__ __forceinline__ void gll16(const void* g, void* l) {
  __builtin_amdgcn_global_load_lds(
      (const __attribute__((address_space(1))) unsigned int*)g,
      (__attribute__((address_space(3))) unsigned int*)l, 16, 0, 0);
}

__device__ __forceinline__ f32x4v mfma16(f16x8v a, f16x8v b, f32x4v c) {
  return __builtin_amdgcn_mfma_f32_16x16x32_f16(a, b, c, 0, 0, 0);
}
__device__ __forceinline__ f32x4v mfma16(bf16x8v a, bf16x8v b, f32x4v c) {
  return __builtin_amdgcn_mfma_f32_16x16x32_bf16(a, b, c, 0, 0, 0);
}

__device__ __forceinline__ unsigned short hbits(float f) {
  __half h = __float2half(f);
  unsigned short b; __builtin_memcpy(&b, &h, 2); return b;
}
__device__ __forceinline__ unsigned short bbits(float f) {
  __hip_bfloat16 h = __float2bfloat16(f);
  unsigned short b; __builtin_memcpy(&b, &h, 2); return b;
}

// ---------------------------------------------------------------------------
// 128x128-tile B^T GEMM, BK-parametric (ROUND-4 PROVEN form: BK=64 +
// chunk-XOR staging swizzle, bank conflicts 0, VGPR 80, LDS 32KB).
// Round-5 lesson: BK=128 halves occupancy -> slower. Round-6 lesson: the
// LDS-staged MODE2 epilogue ADDED issue work (VALUBusy 52->58.6, 62.5->67us)
// -> epilogue store coalescing is NOT a lever; scalar stores are fine.
// MODE 2 is no longer instantiated here (dedicated no-LDS kernel below).
// MODE 0: DUAL theta+phi (blockIdx.z>>2 selects B/bias/out). fp16, +bias[n].
// MODE 1: bf16, +bias[m]                       (g proj -> gB [IC,H])
// MODE 3: fp32, +bias[m] + xres                (final + residual)
// ---------------------------------------------------------------------------
template <int MODE, int BK>
__launch_bounds__(256)
__global__ void mgemm128(const void* __restrict__ Aall, const void* __restrict__ Ball,
                         const void* __restrict__ Ball2,
                         void* __restrict__ outP, void* __restrict__ out2P,
                         const float* __restrict__ bias, const float* __restrict__ bias2,
                         const float* __restrict__ xres, float* __restrict__ Z,
                         int M, int N, int K,
                         size_t sAb, size_t sBb, size_t sOb) {
  using ET = typename std::conditional<MODE == 3, bf16x8v, f16x8v>::type;

  constexpr int CPR = BK / 8;              // 16B chunks per LDS row
  constexpr int XM = (BK >= 64) ? 7 : 0;   // chunk-XOR swizzle mask

  __shared__ __align__(16) unsigned short sA[128 * BK];
  __shared__ __align__(16) unsigned short sB[128 * BK];

  const int zz = blockIdx.z;
  int b, which;
  if constexpr (MODE == 0) { b = zz & (BB - 1); which = zz >> 2; }
  else { b = zz; which = 0; }

  const unsigned short* __restrict__ A = (const unsigned short*)Aall + (size_t)b * sAb;
  const unsigned short* __restrict__ Bm =
      (const unsigned short*)((MODE == 0 && which) ? Ball2 : Ball) + (size_t)b * sBb;
  const float* __restrict__ biasSel = (MODE == 0 && which) ? bias2 : bias;
  void* __restrict__ outSel = (MODE == 0 && which) ? out2P : outP;

  const int t = threadIdx.x;
  const int lane = t & 63;
  const int w = t >> 6;
  const int wm = (w >> 1) << 6;
  const int wn = (w & 1) << 6;
  const int mBase = blockIdx.y * 128;
  const int nBase = blockIdx.x * 128;

  const int fr = lane & 15;
  const int fo = (lane >> 4) << 3;   // 0,8,16,24 shorts within the 32-k slice
  const int fc = fo >> 3;            // 16B sub-chunk index 0..3

  f32x4v acc[4][4] = {};

  for (int k0 = 0; k0 < K; k0 += BK) {
    // stage: 128 rows x BK k per operand = 128*CPR chunks; CPR/2 per thread
#pragma unroll
    for (int p = 0; p < CPR / 2; ++p) {
      const int u = t + (p << 8);
      const int r = u / CPR;
      const int c = u & (CPR - 1);
      const int cs = (c ^ (r & XM)) << 3;
      gll16(A + (size_t)(mBase + r) * K + (k0 + cs), sA + u * 8);
      gll16(Bm + (size_t)(nBase + r) * K + (k0 + cs), sB + u * 8);
    }
    __syncthreads();
#pragma unroll
    for (int ks = 0; ks < BK / 32; ++ks) {
      ET af[4], bf[4];
#pragma unroll
      for (int i = 0; i < 4; ++i) {
        const int row = wm + (i << 4) + fr;
        const int phys = ((ks << 2) + fc) ^ (row & XM);
        af[i] = *(const ET*)(sA + row * BK + (phys << 3));
      }
#pragma unroll
      for (int j = 0; j < 4; ++j) {
        const int row = wn + (j << 4) + fr;
        const int phys = ((ks << 2) + fc) ^ (row & XM);
        bf[j] = *(const ET*)(sB + row * BK + (phys << 3));
      }
#pragma unroll
      for (int i = 0; i < 4; ++i)
#pragma unroll
        for (int j = 0; j < 4; ++j)
          acc[i][j] = mfma16(af[i], bf[j], acc[i][j]);
    }
    __syncthreads();
  }

  const int row0 = (lane >> 4) << 2;
  const int col = lane & 15;

#pragma unroll
  for (int i = 0; i < 4; ++i) {
    const int m0 = mBase + wm + (i << 4) + row0;
#pragma unroll
    for (int j = 0; j < 4; ++j) {
      const int n = nBase + wn + (j << 4) + col;
#pragma unroll
      for (int rg = 0; rg < 4; ++rg) {
        const int m = m0 + rg;
        const float v = acc[i][j][rg];
        if constexpr (MODE == 0) {
          ((__half*)outSel)[(size_t)b * sOb + (size_t)m * N + n] =
              __float2half(v + biasSel[n]);
        } else if constexpr (MODE == 1) {
          ((__hip_bfloat16*)outP)[(size_t)b * sOb + (size_t)m * N + n] =
              __float2bfloat16(v + bias[m]);
        } else {
          const size_t o = (size_t)b * sOb + (size_t)m * N + n;
          ((float*)outP)[o] = v + bias[m] + xres[o];
        }
      }
    }
  }
  (void)Z;
}

// ---------------------------------------------------------------------------
// scores GEMM, NO-LDS direct-fragment version (round 7).
// Rationale: theta/phi are 2MB/batch (L2-resident per XCD); LDS staging gave
// each byte only 2 uses but cost 4 vmcnt(0)-drained barriers per block over
// a short K=256. Here each wave loads MFMA fragments straight from global:
// 8 row base pointers, k advances via 64B immediate offsets -> 64
// global_load_dwordx4, zero barriers, zero LDS; compiler pipelines with
// counted vmcnt. Fragment reads cover full 64B segments (4 lanes x 16B);
// sibling-wave re-reads hit L1/L2.
// E[q][k] = bf16(exp(s)); Z[b,k] += column sums (round-4 proven epilogue:
// scalar 2B stores in 32B quad segments + shfl/atomic reduction).
// ---------------------------------------------------------------------------
__launch_bounds__(256)
__global__ void sgemm_direct(const __half* __restrict__ thetaH,
                             const __half* __restrict__ phiH,
                             __hip_bfloat16* __restrict__ E,
                             float* __restrict__ Z) {
  const int b = blockIdx.z;
  const int t = threadIdx.x;
  const int lane = t & 63;
  const int w = t >> 6;
  const int wm = (w >> 1) << 6;
  const int wn = (w & 1) << 6;
  const int mBase = blockIdx.y * 128;   // q
  const int nBase = blockIdx.x * 128;   // k
  const int fr = lane & 15;
  const int fo = (lane >> 4) << 3;

  const unsigned short* __restrict__ A =
      (const unsigned short*)thetaH + (size_t)b * HH * IC;
  const unsigned short* __restrict__ Bp =
      (const unsigned short*)phiH + (size_t)b * HH * IC;

  // 8 per-lane row base pointers (static-indexed -> registers)
  const unsigned short* ap[4];
  const unsigned short* bp[4];
#pragma unroll
  for (int i = 0; i < 4; ++i)
    ap[i] = A + (size_t)(mBase + wm + (i << 4) + fr) * IC + fo;
#pragma unroll
  for (int j = 0; j < 4; ++j)
    bp[j] = Bp + (size_t)(nBase + wn + (j << 4) + fr) * IC + fo;

  f32x4v acc[4][4] = {};
#pragma unroll
  for (int ks = 0; ks < IC / 32; ++ks) {
    f16x8v af[4], bf[4];
#pragma unroll
    for (int i = 0; i < 4; ++i) af[i] = *(const f16x8v*)(ap[i] + (ks << 5));
#pragma unroll
    for (int j = 0; j < 4; ++j) bf[j] = *(const f16x8v*)(bp[j] + (ks << 5));
#pragma unroll
    for (int i = 0; i < 4; ++i)
#pragma unroll
      for (int j = 0; j < 4; ++j)
        acc[i][j] = mfma16(af[i], bf[j], acc[i][j]);
  }

  // ---- round-4 PROVEN epilogue ----
  const int row0 = (lane >> 4) << 2;
  const int col = lane & 15;
  float csum[4] = {0.f, 0.f, 0.f, 0.f};
#pragma unroll
  for (int i = 0; i < 4; ++i) {
    const int m0 = mBase + wm + (i << 4) + row0;
#pragma unroll
    for (int j = 0; j < 4; ++j) {
      const int n = nBase + wn + (j << 4) + col;
      __hip_bfloat16* dst = E + (size_t)b * HH * HH + (size_t)m0 * HH + n;
#pragma unroll
      for (int rg = 0; rg < 4; ++rg) {
        const float e = __expf(acc[i][j][rg]);
        dst[(size_t)rg * HH] = __float2bfloat16(e);
        csum[j] += e;
      }
    }
  }
#pragma unroll
  for (int j = 0; j < 4; ++j) {
    float s = csum[j];
    s += __shfl_xor(s, 16, 64);
    s += __shfl_xor(s, 32, 64);
    if (lane < 16) {
      const int n = nBase + wn + (j << 4) + col;
      atomicAdd(&Z[(size_t)b * HH + n], s);
    }
  }
}

// ---------------------------------------------------------------------------
// ag GEMM v3 (round-3 PROVEN: 74.6 -> ~45us). BK=128 (256B-contiguous E
// reads) + chunk-XOR swizzled LDS, split-K=2, single-buffered.
// Partial tiles -> fp16 packed ushort4 stores into P16[kc][b][q][ic].
// ---------------------------------------------------------------------------
__launch_bounds__(256)
__global__ void mgemm_ag(const __hip_bfloat16* __restrict__ Gall,
                         const __hip_bfloat16* __restrict__ Eall,
                         unsigned short* __restrict__ P16) {
  constexpr int KC = 2048;
  constexpr int BK = 128;
  __shared__ __align__(16) unsigned short sG[256 * BK];  // 64 KB
  __shared__ __align__(16) unsigned short sE[64 * BK];   // 16 KB

  const int b = blockIdx.z;
  const int kc = blockIdx.x;            // 0..1
  const int qBase = blockIdx.y * 64;
  const int k0base = kc * KC;

  const unsigned short* __restrict__ G =
      (const unsigned short*)Gall + (size_t)b * IC * HH;
  const unsigned short* __restrict__ E =
      (const unsigned short*)Eall + (size_t)b * HH * HH;

  const int t = threadIdx.x;
  const int lane = t & 63;
  const int w = t >> 6;
  const int fr = lane & 15;
  const int fo = (lane >> 4) << 3;      // 0,8,16,24 shorts
  const int fc = fo >> 3;               // chunk sub-index 0..3

  f32x4v acc[4][4] = {};

  for (int kk = 0; kk < KC; kk += BK) {
    const int k0 = k0base + kk;
    // stage E first (HBM, long latency): 64 rows x 128k = 1024 chunks
#pragma unroll
    for (int p = 0; p < 4; ++p) {
      const int u = t + (p << 8);
      const int row = u >> 4;
      const int csrc = (u & 15) ^ (row & 7);
      gll16(E + (size_t)(qBase + row) * HH + k0 + (csrc << 3), sE + u * 8);
    }
    // stage G (mostly L2): 256 rows x 128k = 4096 chunks
#pragma unroll
    for (int p = 0; p < 16; ++p) {
      const int u = t + (p << 8);
      const int row = u >> 4;
      const int csrc = (u & 15) ^ (row & 7);
      gll16(G + (size_t)row * HH + k0 + (csrc << 3), sG + u * 8);
    }
    __syncthreads();
#pragma unroll
    for (int ks = 0; ks < 4; ++ks) {
      bf16x8v af[4], bfv[4];
      const int c16 = (ks << 2) + fc;
#pragma unroll
      for (int i = 0; i < 4; ++i) {
        const int row = (w << 6) + (i << 4) + fr;
        af[i] = *(const bf16x8v*)(sG + row * BK + ((c16 ^ (row & 7)) << 3));
      }
#pragma unroll
      for (int j = 0; j < 4; ++j) {
        const int row = (j << 4) + fr;
        bfv[j] = *(const bf16x8v*)(sE + row * BK + ((c16 ^ (row & 7)) << 3));
      }
#pragma unroll
      for (int i = 0; i < 4; ++i)
#pragma unroll
        for (int j = 0; j < 4; ++j)
          acc[i][j] = mfma16(af[i], bfv[j], acc[i][j]);
    }
    __syncthreads();
  }

  // D layout: col(n=q)=lane&15, row(m=ic)=quad*4+reg -> packed 8B ushort4
  unsigned short* __restrict__ P =
      P16 + ((size_t)kc * BB + b) * HH * IC;
  const int quad = lane >> 4;
  const int col = lane & 15;
#pragma unroll
  for (int i = 0; i < 4; ++i) {
    const int ic0 = (w << 6) + (i << 4) + (quad << 2);
#pragma unroll
    for (int j = 0; j < 4; ++j) {
      const int q = qBase + (j << 4) + col;
      ushort4 s = {hbits(acc[i][j][0]), hbits(acc[i][j][1]),
                   hbits(acc[i][j][2]), hbits(acc[i][j][3])};
      *(ushort4*)(P + (size_t)q * IC + ic0) = s;
    }
  }
}

// agB[b,q,ic] = bf16( sum over 2 split-K chunks of fp16 P16 ), 8 elems/thread
__launch_bounds__(256)
__global__ void cvt_ag(const unsigned short* __restrict__ P16,
                       __hip_bfloat16* __restrict__ agB) {
  constexpr size_t CH = (size_t)BB * HH * IC;
  const size_t tIdx = (size_t)blockIdx.x * 256 + threadIdx.x;
  const f16x8v v0 = ((const f16x8v*)(P16))[tIdx];
  const f16x8v v1 = ((const f16x8v*)(P16 + CH))[tIdx];
  unsigned short o[8];
#pragma unroll
  for (int k = 0; k < 8; ++k) {
    const float s = (float)v0[k] + (float)v1[k];
    o[k] = bbits(s);
  }
  uint4 pack;
  __builtin_memcpy(&pack, o, 16);
  ((uint4*)agB)[tIdx] = pack;
}

// x [B,C,H] fp32 -> xT [B,H,C] fp16
__launch_bounds__(256)
__global__ void xpose(const float* __restrict__ x, __half* __restrict__ xT) {
  __shared__ float tile[64][65];
  const int b = blockIdx.z;
  const int h0 = blockIdx.x * 64;
  const int c0 = blockIdx.y * 64;
  const int lane = threadIdx.x & 63;
  const int r0 = threadIdx.x >> 6;
  const float* xb = x + (size_t)b * CC * HH;
#pragma unroll
  for (int rr = 0; rr < 16; ++rr) {
    const int c = r0 * 16 + rr;
    tile[c][lane] = xb[(size_t)(c0 + c) * HH + h0 + lane];
  }
  __syncthreads();
  __half* ob = xT + (size_t)b * HH * CC;
#pragma unroll
  for (int rr = 0; rr < 16; ++rr) {
    const int hl = r0 * 16 + rr;
    ob[(size_t)(h0 + hl) * CC + c0 + lane] = __float2half(tile[lane][hl]);
  }
}

__global__ void convw(const float* __restrict__ s0, const float* __restrict__ s1,
                      const float* __restrict__ s2, const float* __restrict__ s3,
                      __half* __restrict__ d0, __half* __restrict__ d1,
                      __half* __restrict__ d2, __hip_bfloat16* __restrict__ d3) {
  const int which = blockIdx.y;
  const int i = (blockIdx.x * 256 + threadIdx.x) * 4;
  if (which < 3) {
    const float* s = which == 0 ? s0 : (which == 1 ? s1 : s2);
    __half* d = which == 0 ? d0 : (which == 1 ? d1 : d2);
    const float4 v = *(const float4*)(s + i);
    d[i] = __float2half(v.x); d[i + 1] = __float2half(v.y);
    d[i + 2] = __float2half(v.z); d[i + 3] = __float2half(v.w);
  } else {
    const float4 v = *(const float4*)(s3 + i);
    d3[i] = __float2bfloat16(v.x); d3[i + 1] = __float2bfloat16(v.y);
    d3[i + 2] = __float2bfloat16(v.z); d3[i + 3] = __float2bfloat16(v.w);
  }
}

// gB [B,IC,H] bf16 /= Z[b,h]
__launch_bounds__(256)
__global__ void gscale(unsigned int* __restrict__ g, const float* __restrict__ Z) {
  const size_t tid = (size_t)blockIdx.x * 256 + threadIdx.x;
  const size_t e0 = tid * 8;
  const int b = (int)(e0 >> 20);
  const int h = (int)(e0 & (HH - 1));
  const float* Zp = Z + ((size_t)b << 12) + h;
  uint4 raw = ((const uint4*)g)[tid];
  unsigned short* u = (unsigned short*)&raw;
#pragma unroll
  for (int k = 0; k < 8; ++k) {
    const float f = __uint_as_float(((unsigned)u[k]) << 16) / Zp[k];
    u[k] = bbits(f);
  }
  ((uint4*)g)[tid] = raw;
}

// ---------------------------------------------------------------------------
extern "C" void kernel_launch(void* const* d_in, const int* in_sizes, int n_in,
                              void* d_out, int out_size, void* d_ws, size_t ws_size,
                              hipStream_t stream) {
  (void)in_sizes; (void)n_in; (void)out_size; (void)ws_size;

  const float* x       = (const float*)d_in[0];
  const float* w_phi   = (const float*)d_in[1];
  const float* b_phi   = (const float*)d_in[2];
  const float* w_theta = (const float*)d_in[3];
  const float* b_theta = (const float*)d_in[4];
  const float* w_g     = (const float*)d_in[5];
  const float* b_g     = (const float*)d_in[6];
  const float* w_mask  = (const float*)d_in[7];
  const float* b_mask  = (const float*)d_in[8];
  float* out = (float*)d_out;

  char* p = (char*)d_ws;
  __hip_bfloat16* E = (__hip_bfloat16*)p;           p += (size_t)BB * HH * HH * 2;   // [q][k]
  __half* xT       = (__half*)p;                    p += (size_t)BB * HH * CC * 2;   // 16.8 MB
  __half* thetaH   = (__half*)p;                    p += (size_t)BB * HH * IC * 2;   // [h][ic]
  __half* phiH     = (__half*)p;                    p += (size_t)BB * HH * IC * 2;   // [h][ic]
  __hip_bfloat16* gB  = (__hip_bfloat16*)p;         p += (size_t)BB * IC * HH * 2;   // [ic][h]
  __hip_bfloat16* agB = (__hip_bfloat16*)p;         p += (size_t)BB * HH * IC * 2;   // [h][ic]
  __half* wthH = (__half*)p;                        p += (size_t)IC * CC * 2;
  __half* wphH = (__half*)p;                        p += (size_t)IC * CC * 2;
  __half* wgH  = (__half*)p;                        p += (size_t)IC * CC * 2;
  __hip_bfloat16* wmB = (__hip_bfloat16*)p;         p += (size_t)CC * IC * 2;
  float* Z = (float*)p;                             p += (size_t)BB * HH * 4;
  // fp16 split-K=2 partials (2 x 8.4 MB = 16.8 MB) alias xT exactly; xT is
  // dead by the time mgemm_ag runs.
  unsigned short* P16 = (unsigned short*)xT;

  const dim3 blk(256);

  convw<<<dim3(128, 4), blk, 0, stream>>>(w_phi, w_theta, w_g, w_mask, wphH, wthH, wgH, wmB);
  xpose<<<dim3(HH / 64, CC / 64, BB), blk, 0, stream>>>(x, xT);

  // theta/phi dual: A=xT [H,C], B=w_theta/w_phi [IC,C]; out [h][ic] fp16, +bias[ic]
  mgemm128<0, 64><<<dim3(IC / 128, HH / 128, BB * 2), blk, 0, stream>>>(
      xT, wthH, wphH, thetaH, phiH, b_theta, b_phi, nullptr, nullptr,
      HH, IC, CC, (size_t)HH * CC, 0, (size_t)HH * IC);

  // g: A=wg [IC,C], B=xT [H,C]; out gB[ic][h] bf16, +bias[ic=m]
  mgemm128<1, 64><<<dim3(HH / 128, IC / 128, BB), blk, 0, stream>>>(
      wgH, xT, nullptr, gB, nullptr, b_g, nullptr, nullptr, nullptr,
      IC, HH, CC, 0, (size_t)HH * CC, (size_t)IC * HH);

  // scores: NO-LDS direct-fragment kernel; E[q][k] bf16 + Z[b,k]
  hipMemsetAsync(Z, 0, (size_t)BB * HH * sizeof(float), stream);
  sgemm_direct<<<dim3(HH / 128, HH / 128, BB), blk, 0, stream>>>(
      thetaH, phiH, E, Z);

  gscale<<<dim3((BB * IC * HH / 8) / 256), blk, 0, stream>>>((unsigned int*)gB, Z);

  // ag: BK=128 (256B-contiguous E reads), split-K=2, XOR-swizzled LDS
  mgemm_ag<<<dim3(2, HH / 64, BB), blk, 0, stream>>>(gB, E, P16);
  cvt_ag<<<dim3((BB * HH * IC / 8) / 256), blk, 0, stream>>>(P16, agB);

  // final: A=wm [C,IC], B=agB [H,IC]; out[c][h] fp32 + bias[c] + x
  mgemm128<3, 64><<<dim3(HH / 128, CC / 128, BB), blk, 0, stream>>>(
      wmB, agB, nullptr, out, nullptr, b_mask, nullptr, x, nullptr,
      CC, HH, IC, 0, (size_t)HH * IC, (size_t)CC * HH);
}

// Round 8
// 252.520 us; speedup vs baseline: 1.2893x; 1.2893x over previous
//
#include <hip/hip_runtime.h>
#include <hip/hip_bf16.h>
#include <hip/hip_fp16.h>
#include <type_traits>

constexpr int BB = 4;
constexpr int CC = 512;
constexpr int HH = 4096;
constexpr int IC = 256;

typedef _Float16 f16x8v __attribute__((ext_vector_type(8)));
typedef __bf16   bf16x8v __attribute__((ext_vector_type(8)));
typedef float    f32x4v __attribute__((ext_vector_type(4)));

__device__ __forceinline__ void gll16(const void* g, void* l) {
  __builtin_amdgcn_global_load_lds(
      (const __attribute__((address_space(1))) unsigned int*)g,
      (__attribute__((address_space(3))) unsigned int*)l, 16, 0, 0);
}

__device__ __forceinline__ f32x4v mfma16(f16x8v a, f16x8v b, f32x4v c) {
  return __builtin_amdgcn_mfma_f32_16x16x32_f16(a, b, c, 0, 0, 0);
}
__device__ __forceinline__ f32x4v mfma16(bf16x8v a, bf16x8v b, f32x4v c) {
  return __builtin_amdgcn_mfma_f32_16x16x32_bf16(a, b, c, 0, 0, 0);
}

__device__ __forceinline__ unsigned short hbits(float f) {
  __half h = __float2half(f);
  unsigned short b; __builtin_memcpy(&b, &h, 2); return b;
}
__device__ __forceinline__ unsigned short bbits(float f) {
  __hip_bfloat16 h = __float2bfloat16(f);
  unsigned short b; __builtin_memcpy(&b, &h, 2); return b;
}

// ---------------------------------------------------------------------------
// 128x128-tile B^T GEMM (ROUND-4 PROVEN: BK=64 + chunk-XOR staging swizzle,
// bank conflicts 0, VGPR 80, LDS 32KB, MODE2 62.5us).
// Failed levers (do not retry): BK=128 (r5: occupancy halves), LDS-staged
// MODE2 epilogue (r6: adds issue work), no-LDS direct fragments (r7:
// scattered per-lane loads, 139us), swapped packed epilogue (r1: WRITE_SIZE
// +50%). MODE2 is ~74% combined MFMA+VALU issue utilization — near this
// structure's ceiling.
// MODE 0: DUAL theta+phi (blockIdx.z>>2 selects B/bias/out). fp16, +bias[n].
// MODE 1: bf16, +bias[m]                       (g proj -> gB [IC,H])
// MODE 2: bf16 exp(v); Z[b,n] += column sums   (scores -> E [q,k])
// MODE 3: fp32, +bias[m] + xres; B operand = SUM OF TWO fp16 SPLIT-K
//         PARTIALS (P16 halves) reg-staged with in-register add (round 8:
//         kills cvt_ag kernel + agB buffer).
// ---------------------------------------------------------------------------
template <int MODE, int BK>
__launch_bounds__(256)
__global__ void mgemm128(const void* __restrict__ Aall, const void* __restrict__ Ball,
                         const void* __restrict__ Ball2,
                         void* __restrict__ outP, void* __restrict__ out2P,
                         const float* __restrict__ bias, const float* __restrict__ bias2,
                         const float* __restrict__ xres, float* __restrict__ Z,
                         int M, int N, int K,
                         size_t sAb, size_t sBb, size_t sOb) {
  constexpr int CPR = BK / 8;              // 16B chunks per LDS row
  constexpr int XM = (BK >= 64) ? 7 : 0;   // chunk-XOR swizzle mask

  __shared__ __align__(16) unsigned short sA[128 * BK];
  __shared__ __align__(16) unsigned short sB[128 * BK];

  const int zz = blockIdx.z;
  int b, which;
  if constexpr (MODE == 0) { b = zz & (BB - 1); which = zz >> 2; }
  else { b = zz; which = 0; }

  const unsigned short* __restrict__ A = (const unsigned short*)Aall + (size_t)b * sAb;
  const unsigned short* __restrict__ Bm =
      (const unsigned short*)((MODE == 0 && which) ? Ball2 : Ball) + (size_t)b * sBb;
  const float* __restrict__ biasSel = (MODE == 0 && which) ? bias2 : bias;
  void* __restrict__ outSel = (MODE == 0 && which) ? out2P : outP;

  const int t = threadIdx.x;
  const int lane = t & 63;
  const int w = t >> 6;
  const int wm = (w >> 1) << 6;
  const int wn = (w & 1) << 6;
  const int mBase = blockIdx.y * 128;
  const int nBase = blockIdx.x * 128;

  const int fr = lane & 15;
  const int fo = (lane >> 4) << 3;   // 0,8,16,24 shorts within the 32-k slice
  const int fc = fo >> 3;            // 16B sub-chunk index 0..3

  f32x4v acc[4][4] = {};

  for (int k0 = 0; k0 < K; k0 += BK) {
    // stage: 128 rows x BK k per operand = 128*CPR chunks; CPR/2 per thread
#pragma unroll
    for (int p = 0; p < CPR / 2; ++p) {
      const int u = t + (p << 8);
      const int r = u / CPR;
      const int c = u & (CPR - 1);
      const int cs = (c ^ (r & XM)) << 3;
      gll16(A + (size_t)(mBase + r) * K + (k0 + cs), sA + u * 8);
      if constexpr (MODE == 3) {
        // B = P16 half0 + half1 (fp16), reg-staged with vector add; LDS
        // layout identical to the gll16 path (linear dest, pre-XOR'd src).
        const unsigned short* s0 = Bm + (size_t)(nBase + r) * K + (k0 + cs);
        const f16x8v v0 = *(const f16x8v*)s0;
        const f16x8v v1 = *(const f16x8v*)(s0 + (size_t)BB * HH * IC);
        *(f16x8v*)(sB + u * 8) = v0 + v1;
      } else {
        gll16(Bm + (size_t)(nBase + r) * K + (k0 + cs), sB + u * 8);
      }
    }
    __syncthreads();
#pragma unroll
    for (int ks = 0; ks < BK / 32; ++ks) {
      f16x8v af[4], bf[4];
#pragma unroll
      for (int i = 0; i < 4; ++i) {
        const int row = wm + (i << 4) + fr;
        const int phys = ((ks << 2) + fc) ^ (row & XM);
        af[i] = *(const f16x8v*)(sA + row * BK + (phys << 3));
      }
#pragma unroll
      for (int j = 0; j < 4; ++j) {
        const int row = wn + (j << 4) + fr;
        const int phys = ((ks << 2) + fc) ^ (row & XM);
        bf[j] = *(const f16x8v*)(sB + row * BK + (phys << 3));
      }
#pragma unroll
      for (int i = 0; i < 4; ++i)
#pragma unroll
        for (int j = 0; j < 4; ++j)
          acc[i][j] = mfma16(af[i], bf[j], acc[i][j]);
    }
    __syncthreads();
  }

  const int row0 = (lane >> 4) << 2;
  const int col = lane & 15;

  if constexpr (MODE == 2) {
    __hip_bfloat16* __restrict__ outB = (__hip_bfloat16*)outP;
    float csum[4] = {0.f, 0.f, 0.f, 0.f};
#pragma unroll
    for (int i = 0; i < 4; ++i) {
      const int m0 = mBase + wm + (i << 4) + row0;
#pragma unroll
      for (int j = 0; j < 4; ++j) {
        const int n = nBase + wn + (j << 4) + col;
        __hip_bfloat16* dst = outB + (size_t)b * sOb + (size_t)m0 * N + n;
#pragma unroll
        for (int rg = 0; rg < 4; ++rg) {
          const float e = __expf(acc[i][j][rg]);
          dst[(size_t)rg * N] = __float2bfloat16(e);
          csum[j] += e;
        }
      }
    }
#pragma unroll
    for (int j = 0; j < 4; ++j) {
      float s = csum[j];
      s += __shfl_xor(s, 16, 64);
      s += __shfl_xor(s, 32, 64);
      if (lane < 16) {
        const int n = nBase + wn + (j << 4) + col;
        atomicAdd(&Z[(size_t)b * N + n], s);
      }
    }
  } else {
#pragma unroll
    for (int i = 0; i < 4; ++i) {
      const int m0 = mBase + wm + (i << 4) + row0;
#pragma unroll
      for (int j = 0; j < 4; ++j) {
        const int n = nBase + wn + (j << 4) + col;
#pragma unroll
        for (int rg = 0; rg < 4; ++rg) {
          const int m = m0 + rg;
          const float v = acc[i][j][rg];
          if constexpr (MODE == 0) {
            ((__half*)outSel)[(size_t)b * sOb + (size_t)m * N + n] =
                __float2half(v + biasSel[n]);
          } else if constexpr (MODE == 1) {
            ((__hip_bfloat16*)outP)[(size_t)b * sOb + (size_t)m * N + n] =
                __float2bfloat16(v + bias[m]);
          } else {
            const size_t o = (size_t)b * sOb + (size_t)m * N + n;
            ((float*)outP)[o] = v + bias[m] + xres[o];
          }
        }
      }
    }
  }
  (void)M;
}

// ---------------------------------------------------------------------------
// ag GEMM v3 (round-3 PROVEN: 74.6 -> ~45us). BK=128 (256B-contiguous E
// reads) + chunk-XOR swizzled LDS, split-K=2, single-buffered.
// Partial tiles -> fp16 packed ushort4 stores into P16[kc][b][q][ic].
// P16 is consumed DIRECTLY by mgemm128<3> (round 8) — no cvt kernel.
// ---------------------------------------------------------------------------
__launch_bounds__(256)
__global__ void mgemm_ag(const __hip_bfloat16* __restrict__ Gall,
                         const __hip_bfloat16* __restrict__ Eall,
                         unsigned short* __restrict__ P16) {
  constexpr int KC = 2048;
  constexpr int BK = 128;
  __shared__ __align__(16) unsigned short sG[256 * BK];  // 64 KB
  __shared__ __align__(16) unsigned short sE[64 * BK];   // 16 KB

  const int b = blockIdx.z;
  const int kc = blockIdx.x;            // 0..1
  const int qBase = blockIdx.y * 64;
  const int k0base = kc * KC;

  const unsigned short* __restrict__ G =
      (const unsigned short*)Gall + (size_t)b * IC * HH;
  const unsigned short* __restrict__ E =
      (const unsigned short*)Eall + (size_t)b * HH * HH;

  const int t = threadIdx.x;
  const int lane = t & 63;
  const int w = t >> 6;
  const int fr = lane & 15;
  const int fo = (lane >> 4) << 3;      // 0,8,16,24 shorts
  const int fc = fo >> 3;               // chunk sub-index 0..3

  f32x4v acc[4][4] = {};

  for (int kk = 0; kk < KC; kk += BK) {
    const int k0 = k0base + kk;
    // stage E first (HBM, long latency): 64 rows x 128k = 1024 chunks
#pragma unroll
    for (int p = 0; p < 4; ++p) {
      const int u = t + (p << 8);
      const int row = u >> 4;
      const int csrc = (u & 15) ^ (row & 7);
      gll16(E + (size_t)(qBase + row) * HH + k0 + (csrc << 3), sE + u * 8);
    }
    // stage G (mostly L2): 256 rows x 128k = 4096 chunks
#pragma unroll
    for (int p = 0; p < 16; ++p) {
      const int u = t + (p << 8);
      const int row = u >> 4;
      const int csrc = (u & 15) ^ (row & 7);
      gll16(G + (size_t)row * HH + k0 + (csrc << 3), sG + u * 8);
    }
    __syncthreads();
#pragma unroll
    for (int ks = 0; ks < 4; ++ks) {
      bf16x8v af[4], bfv[4];
      const int c16 = (ks << 2) + fc;
#pragma unroll
      for (int i = 0; i < 4; ++i) {
        const int row = (w << 6) + (i << 4) + fr;
        af[i] = *(const bf16x8v*)(sG + row * BK + ((c16 ^ (row & 7)) << 3));
      }
#pragma unroll
      for (int j = 0; j < 4; ++j) {
        const int row = (j << 4) + fr;
        bfv[j] = *(const bf16x8v*)(sE + row * BK + ((c16 ^ (row & 7)) << 3));
      }
#pragma unroll
      for (int i = 0; i < 4; ++i)
#pragma unroll
        for (int j = 0; j < 4; ++j)
          acc[i][j] = mfma16(af[i], bfv[j], acc[i][j]);
    }
    __syncthreads();
  }

  // D layout: col(n=q)=lane&15, row(m=ic)=quad*4+reg -> packed 8B ushort4
  unsigned short* __restrict__ P =
      P16 + ((size_t)kc * BB + b) * HH * IC;
  const int quad = lane >> 4;
  const int col = lane & 15;
#pragma unroll
  for (int i = 0; i < 4; ++i) {
    const int ic0 = (w << 6) + (i << 4) + (quad << 2);
#pragma unroll
    for (int j = 0; j < 4; ++j) {
      const int q = qBase + (j << 4) + col;
      ushort4 s = {hbits(acc[i][j][0]), hbits(acc[i][j][1]),
                   hbits(acc[i][j][2]), hbits(acc[i][j][3])};
      *(ushort4*)(P + (size_t)q * IC + ic0) = s;
    }
  }
}

// x [B,C,H] fp32 -> xT [B,H,C] fp16
__launch_bounds__(256)
__global__ void xpose(const float* __restrict__ x, __half* __restrict__ xT) {
  __shared__ float tile[64][65];
  const int b = blockIdx.z;
  const int h0 = blockIdx.x * 64;
  const int c0 = blockIdx.y * 64;
  const int lane = threadIdx.x & 63;
  const int r0 = threadIdx.x >> 6;
  const float* xb = x + (size_t)b * CC * HH;
#pragma unroll
  for (int rr = 0; rr < 16; ++rr) {
    const int c = r0 * 16 + rr;
    tile[c][lane] = xb[(size_t)(c0 + c) * HH + h0 + lane];
  }
  __syncthreads();
  __half* ob = xT + (size_t)b * HH * CC;
#pragma unroll
  for (int rr = 0; rr < 16; ++rr) {
    const int hl = r0 * 16 + rr;
    ob[(size_t)(h0 + hl) * CC + c0 + lane] = __float2half(tile[lane][hl]);
  }
}

// all four weights -> fp16 (w_mask now fp16 too: MODE3 runs f16 x f16 MFMA)
__global__ void convw(const float* __restrict__ s0, const float* __restrict__ s1,
                      const float* __restrict__ s2, const float* __restrict__ s3,
                      __half* __restrict__ d0, __half* __restrict__ d1,
                      __half* __restrict__ d2, __half* __restrict__ d3) {
  const int which = blockIdx.y;
  const int i = (blockIdx.x * 256 + threadIdx.x) * 4;
  const float* s = which == 0 ? s0 : (which == 1 ? s1 : (which == 2 ? s2 : s3));
  __half* d = which == 0 ? d0 : (which == 1 ? d1 : (which == 2 ? d2 : d3));
  const float4 v = *(const float4*)(s + i);
  d[i] = __float2half(v.x); d[i + 1] = __float2half(v.y);
  d[i + 2] = __float2half(v.z); d[i + 3] = __float2half(v.w);
}

// gB [B,IC,H] bf16 /= Z[b,h]
__launch_bounds__(256)
__global__ void gscale(unsigned int* __restrict__ g, const float* __restrict__ Z) {
  const size_t tid = (size_t)blockIdx.x * 256 + threadIdx.x;
  const size_t e0 = tid * 8;
  const int b = (int)(e0 >> 20);
  const int h = (int)(e0 & (HH - 1));
  const float* Zp = Z + ((size_t)b << 12) + h;
  uint4 raw = ((const uint4*)g)[tid];
  unsigned short* u = (unsigned short*)&raw;
#pragma unroll
  for (int k = 0; k < 8; ++k) {
    const float f = __uint_as_float(((unsigned)u[k]) << 16) / Zp[k];
    u[k] = bbits(f);
  }
  ((uint4*)g)[tid] = raw;
}

// ---------------------------------------------------------------------------
extern "C" void kernel_launch(void* const* d_in, const int* in_sizes, int n_in,
                              void* d_out, int out_size, void* d_ws, size_t ws_size,
                              hipStream_t stream) {
  (void)in_sizes; (void)n_in; (void)out_size; (void)ws_size;

  const float* x       = (const float*)d_in[0];
  const float* w_phi   = (const float*)d_in[1];
  const float* b_phi   = (const float*)d_in[2];
  const float* w_theta = (const float*)d_in[3];
  const float* b_theta = (const float*)d_in[4];
  const float* w_g     = (const float*)d_in[5];
  const float* b_g     = (const float*)d_in[6];
  const float* w_mask  = (const float*)d_in[7];
  const float* b_mask  = (const float*)d_in[8];
  float* out = (float*)d_out;

  char* p = (char*)d_ws;
  __hip_bfloat16* E = (__hip_bfloat16*)p;           p += (size_t)BB * HH * HH * 2;   // [q][k]
  __half* xT       = (__half*)p;                    p += (size_t)BB * HH * CC * 2;   // 16.8 MB
  __half* thetaH   = (__half*)p;                    p += (size_t)BB * HH * IC * 2;   // [h][ic]
  __half* phiH     = (__half*)p;                    p += (size_t)BB * HH * IC * 2;   // [h][ic]
  __hip_bfloat16* gB  = (__hip_bfloat16*)p;         p += (size_t)BB * IC * HH * 2;   // [ic][h]
  __half* wthH = (__half*)p;                        p += (size_t)IC * CC * 2;
  __half* wphH = (__half*)p;                        p += (size_t)IC * CC * 2;
  __half* wgH  = (__half*)p;                        p += (size_t)IC * CC * 2;
  __half* wmH  = (__half*)p;                        p += (size_t)CC * IC * 2;
  float* Z = (float*)p;                             p += (size_t)BB * HH * 4;
  // fp16 split-K=2 partials (2 x 8.4 MB = 16.8 MB) alias xT exactly; xT is
  // dead by the time mgemm_ag runs. Consumed directly by mgemm128<3>.
  unsigned short* P16 = (unsigned short*)xT;

  const dim3 blk(256);

  convw<<<dim3(128, 4), blk, 0, stream>>>(w_phi, w_theta, w_g, w_mask, wphH, wthH, wgH, wmH);
  xpose<<<dim3(HH / 64, CC / 64, BB), blk, 0, stream>>>(x, xT);

  // theta/phi dual: A=xT [H,C], B=w_theta/w_phi [IC,C]; out [h][ic] fp16, +bias[ic]
  mgemm128<0, 64><<<dim3(IC / 128, HH / 128, BB * 2), blk, 0, stream>>>(
      xT, wthH, wphH, thetaH, phiH, b_theta, b_phi, nullptr, nullptr,
      HH, IC, CC, (size_t)HH * CC, 0, (size_t)HH * IC);

  // g: A=wg [IC,C], B=xT [H,C]; out gB[ic][h] bf16, +bias[ic=m]
  mgemm128<1, 64><<<dim3(HH / 128, IC / 128, BB), blk, 0, stream>>>(
      wgH, xT, nullptr, gB, nullptr, b_g, nullptr, nullptr, nullptr,
      IC, HH, CC, 0, (size_t)HH * CC, (size_t)IC * HH);

  // scores: A=theta (m=q), B=phi (n=k); E[q][k] bf16 + Z[b,k]
  hipMemsetAsync(Z, 0, (size_t)BB * HH * sizeof(float), stream);
  mgemm128<2, 64><<<dim3(HH / 128, HH / 128, BB), blk, 0, stream>>>(
      thetaH, phiH, nullptr, E, nullptr, nullptr, nullptr, nullptr, Z,
      HH, HH, IC, (size_t)HH * IC, (size_t)HH * IC, (size_t)HH * HH);

  gscale<<<dim3((BB * IC * HH / 8) / 256), blk, 0, stream>>>((unsigned int*)gB, Z);

  // ag: BK=128 (256B-contiguous E reads), split-K=2, XOR-swizzled LDS
  mgemm_ag<<<dim3(2, HH / 64, BB), blk, 0, stream>>>(gB, E, P16);

  // final: A=wm [C,IC] fp16, B = P16 half0+half1 (fp16, reg-staged add);
  // out[c][h] fp32 + bias[c] + x
  mgemm128<3, 64><<<dim3(HH / 128, CC / 128, BB), blk, 0, stream>>>(
      wmH, P16, nullptr, out, nullptr, b_mask, nullptr, x, nullptr,
      CC, HH, IC, 0, (size_t)HH * IC, (size_t)CC * HH);
}